// Round 2
// baseline (285.436 us; speedup 1.0000x reference)
//
#include <hip/hip_runtime.h>
#include <hip/hip_bf16.h>
#include <hip/hip_cooperative_groups.h>

namespace cg = cooperative_groups;

// Shapes (fixed by reference): B=8, N=1024, Din=256, H=4, Dh=128, Do=64
#define BSZ 8
#define NN 1024
#define DIN 256
#define NH 4
#define DH 128
#define DOUT 64
#define RTOT (BSZ*NN)          // 8192 rows total
#define FCAT (NH*DH)           // 512
#define ALPHA 0.2f

typedef unsigned short ushortT;
typedef __attribute__((ext_vector_type(8))) short bf16x8;
typedef __attribute__((ext_vector_type(4))) float f32x4;

static __device__ __forceinline__ ushortT f2bf(float f) {
    __hip_bfloat16 h = __float2bfloat16(f);
    return *reinterpret_cast<ushortT*>(&h);
}
static __device__ __forceinline__ float bfu2f(ushortT u) {
    return __uint_as_float(((unsigned)u) << 16);
}
static __device__ __forceinline__ void split2(float v, ushortT& hi, ushortT& lo) {
    hi = f2bf(v);
    lo = f2bf(v - bfu2f(hi));
}
// async global->LDS, 16B per lane; LDS dest = base(wave-uniform) + lane*16
static __device__ __forceinline__ void gload16(const ushortT* g, ushortT* l) {
    __builtin_amdgcn_global_load_lds(
        (const __attribute__((address_space(1))) unsigned int*)(const void*)g,
        (__attribute__((address_space(3))) unsigned int*)(void*)l, 16, 0, 0);
}

// ================= single persistent cooperative kernel: all 5 stages =================
// grid 256 blocks x 512 thr (1 block/CU, 2 waves/SIMD). grid.sync() between stages.
// LDS: one 87.4 KB arena re-carved per stage.
__global__ __launch_bounds__(512, 2) void k_mega(
        const float* __restrict__ x, const int* __restrict__ adj,
        const float* __restrict__ W, const float* __restrict__ ah_,
        const float* __restrict__ Wout, const float* __restrict__ aout,
        const float* __restrict__ Wf, const float* __restrict__ bfv,
        float* __restrict__ out,
        ushortT* __restrict__ xbh, ushortT* __restrict__ xbl,
        ushortT* __restrict__ WbTh, ushortT* __restrict__ WbTl,
        ushortT* __restrict__ WoTh, ushortT* __restrict__ WoTl,
        unsigned* __restrict__ adjbit,
        ushortT* __restrict__ WhT, float* __restrict__ src1, float* __restrict__ dst1,
        ushortT* __restrict__ xcat, ushortT* __restrict__ Wh2T,
        float* __restrict__ src2, float* __restrict__ dst2) {
    __shared__ __align__(16) char smem[87424];
    const int tid = threadIdx.x, lane = tid & 63, wave = tid >> 6;
    const int bx = blockIdx.x;
    const int m16 = lane & 15, quad = lane >> 4;
    cg::grid_group grid = cg::this_grid();

    // ---------------- S0: prep (x->bf16 hi/lo, W/Wout transforms, adj bitpack) ----------------
    {
        const int gth = bx * 512 + tid;               // 0..131071
#pragma unroll
        for (int r = 0; r < 2; ++r) {                 // x: 262144 groups of 8 floats
            const int g = r * 131072 + gth;
            const float4* p = (const float4*)x + (size_t)g * 2;
            union { ushortT u[8]; uint4 q; } th, tl;
#pragma unroll
            for (int e4 = 0; e4 < 2; ++e4) {
                const float4 v = p[e4];
                split2(v.x, th.u[e4 * 4 + 0], tl.u[e4 * 4 + 0]);
                split2(v.y, th.u[e4 * 4 + 1], tl.u[e4 * 4 + 1]);
                split2(v.z, th.u[e4 * 4 + 2], tl.u[e4 * 4 + 2]);
                split2(v.w, th.u[e4 * 4 + 3], tl.u[e4 * 4 + 3]);
            }
            ((uint4*)xbh)[g] = th.q;
            ((uint4*)xbl)[g] = tl.q;
        }
        {   // W transform: 131072 elems, one per thread
            const int h = gth >> 15, f = (gth >> 8) & 127, k = gth & 255;
            const int kt = k >> 6, k64 = k & 63;
            const float v = W[(size_t)h * DIN * DH + (size_t)k * DH + f];
            ushortT hi, lo; split2(v, hi, lo);
            const int idx = ((h * 4 + kt) * 128 + f) * 64 + k64;
            WbTh[idx] = hi; WbTl[idx] = lo;
        }
        if (gth < DOUT * FCAT) {                      // Wout: 32768 elems
            const int f = gth >> 9, k = gth & 511;
            const float v = Wout[(size_t)k * DOUT + f];
            ushortT hi, lo; split2(v, hi, lo);
            WoTh[gth] = hi; WoTl[gth] = lo;
        }
#pragma unroll
        for (int r = 0; r < 2; ++r) {                 // adj bitpack: 262144 words
            const int gw = r * 131072 + gth;
            const int row = gw >> 5, w = gw & 31;
            const int4* p = (const int4*)(adj + (size_t)row * NN + w * 32);
            unsigned m = 0;
#pragma unroll
            for (int q = 0; q < 8; ++q) {
                const int4 v = p[q];
                m |= (v.x > 0 ? 1u : 0u) << (q * 4 + 0);
                m |= (v.y > 0 ? 1u : 0u) << (q * 4 + 1);
                m |= (v.z > 0 ? 1u : 0u) << (q * 4 + 2);
                m |= (v.w > 0 ? 1u : 0u) << (q * 4 + 3);
            }
            adjbit[gw] = m;
        }
    }
    grid.sync();

    // ---------------- S1: wh1 GEMM (block = (h, 128-row tile)) ----------------
    {
        ushortT* Ah = (ushortT*)smem;                 // 16 KB each
        ushortT* Al = Ah + 128 * 64;
        ushortT* Bh = Al + 128 * 64;
        ushortT* Bl = Bh + 128 * 64;
        float* sred = (float*)(smem + 65536);         // [8][32]
        float* dred = sred + 256;
        const int h = bx >> 6, mt = bx & 63;
        const int r0 = mt * 128, b = r0 >> 10, jr = r0 & 1023;
        const int mg = wave >> 1, fg = wave & 1;
        f32x4 acc[2][4];
#pragma unroll
        for (int a = 0; a < 2; ++a)
#pragma unroll
            for (int c = 0; c < 4; ++c) acc[a][c] = (f32x4){0.f, 0.f, 0.f, 0.f};

        for (int kt = 0; kt < 4; ++kt) {
            __syncthreads();
            const ushortT* planeH = WbTh + (size_t)((h * 4 + kt) * 128) * 64;
            const ushortT* planeL = WbTl + (size_t)((h * 4 + kt) * 128) * 64;
#pragma unroll
            for (int half = 0; half < 2; ++half) {
                const int f = wave * 16 + half * 8 + (lane >> 3);
                const int sc = (lane & 7) ^ (f & 7);
                gload16(planeH + (size_t)f * 64 + sc * 8, Bh + (wave * 16 + half * 8) * 64);
                gload16(planeL + (size_t)f * 64 + sc * 8, Bl + (wave * 16 + half * 8) * 64);
            }
#pragma unroll
            for (int half = 0; half < 2; ++half) {
                const int r = wave * 16 + half * 8 + (lane >> 3);
                const int sc = (lane & 7) ^ (r & 7);
                gload16(xbh + (size_t)(r0 + r) * DIN + kt * 64 + sc * 8, Ah + (wave * 16 + half * 8) * 64);
                gload16(xbl + (size_t)(r0 + r) * DIN + kt * 64 + sc * 8, Al + (wave * 16 + half * 8) * 64);
            }
            __syncthreads();
#pragma unroll
            for (int ks = 0; ks < 2; ++ks) {
                bf16x8 a_h[2], a_l[2], b_h[4], b_l[4];
#pragma unroll
                for (int ms = 0; ms < 2; ++ms) {
                    const int row = (mg * 2 + ms) * 16 + m16;
                    const int cl = (ks * 4 + quad) ^ (row & 7);
                    a_h[ms] = *(const bf16x8*)&Ah[row * 64 + cl * 8];
                    a_l[ms] = *(const bf16x8*)&Al[row * 64 + cl * 8];
                }
#pragma unroll
                for (int fs = 0; fs < 4; ++fs) {
                    const int row = (fg * 4 + fs) * 16 + m16;
                    const int cl = (ks * 4 + quad) ^ (row & 7);
                    b_h[fs] = *(const bf16x8*)&Bh[row * 64 + cl * 8];
                    b_l[fs] = *(const bf16x8*)&Bl[row * 64 + cl * 8];
                }
#pragma unroll
                for (int ms = 0; ms < 2; ++ms)
#pragma unroll
                    for (int fs = 0; fs < 4; ++fs) {
                        acc[ms][fs] = __builtin_amdgcn_mfma_f32_16x16x32_bf16(a_h[ms], b_h[fs], acc[ms][fs], 0, 0, 0);
                        acc[ms][fs] = __builtin_amdgcn_mfma_f32_16x16x32_bf16(a_h[ms], b_l[fs], acc[ms][fs], 0, 0, 0);
                        acc[ms][fs] = __builtin_amdgcn_mfma_f32_16x16x32_bf16(a_l[ms], b_h[fs], acc[ms][fs], 0, 0, 0);
                    }
            }
        }
        float sacc[2][4] = {{0,0,0,0},{0,0,0,0}}, dacc[2][4] = {{0,0,0,0},{0,0,0,0}};
#pragma unroll
        for (int ms = 0; ms < 2; ++ms)
#pragma unroll
            for (int fs = 0; fs < 4; ++fs) {
                const int fl = (fg * 4 + fs) * 16 + m16;
                const float a_s = ah_[h * 2 * DH + fl];
                const float a_d = ah_[h * 2 * DH + DH + fl];
                union { ushortT u[4]; uint2 q; } tw;
#pragma unroll
                for (int reg = 0; reg < 4; ++reg) {
                    const float v = acc[ms][fs][reg];
                    sacc[ms][reg] += v * a_s;
                    dacc[ms][reg] += v * a_d;
                    tw.u[reg] = f2bf(v);
                }
                *(uint2*)(WhT + ((size_t)((b * NH + h) * DH + fl)) * NN + jr + (mg * 2 + ms) * 16 + quad * 4) = tw.q;
            }
#pragma unroll
        for (int ms = 0; ms < 2; ++ms) {
#pragma unroll
            for (int reg = 0; reg < 4; ++reg) {
                float s = sacc[ms][reg], d = dacc[ms][reg];
#pragma unroll
                for (int o = 8; o > 0; o >>= 1) {
                    s += __shfl_xor(s, o, 64);
                    d += __shfl_xor(d, o, 64);
                }
                if (m16 == 0) {
                    sred[wave * 32 + ms * 16 + quad * 4 + reg] = s;
                    dred[wave * 32 + ms * 16 + quad * 4 + reg] = d;
                }
            }
        }
        __syncthreads();
        if (tid < 128) {
            const int mgr = tid >> 5, idx = tid & 31;
            src1[h * RTOT + r0 + tid] = sred[mgr * 2 * 32 + idx] + sred[(mgr * 2 + 1) * 32 + idx];
            dst1[h * RTOT + r0 + tid] = dred[mgr * 2 * 32 + idx] + dred[(mgr * 2 + 1) * 32 + idx];
        }
    }
    grid.sync();

    // ---------------- S2: attn1 (fused softmax + PV), tile M=128, F=128, K=1024 ----------------
    {
        ushortT* As2 = (ushortT*)smem;                        // [2][128*64] 32 KB
        ushortT* Bs2 = As2 + 2 * 128 * 64;                    // [2][128*64] 32 KB
        unsigned* mask2 = (unsigned*)(smem + 65536);          // [128*32] 16 KB
        float* dstv2 = (float*)(smem + 65536 + 16384);        // [1024] 4 KB
        float* srcv2 = dstv2 + 1024;                          // [128]
        float* rowinv2 = srcv2 + 128;                         // [128]
        float* red8 = rowinv2 + 128;                          // [8]
        const int bh = bx & 31, it = bx >> 5;
        const int b = bh >> 2, h = bh & 3;
        const int i0 = it * 128;

        const unsigned* mbase = adjbit + (size_t)(b * NN + i0) * 32;
#pragma unroll
        for (int k2 = 0; k2 < 8; ++k2) mask2[tid + 512 * k2] = mbase[tid + 512 * k2];
        float lm = -INFINITY;
#pragma unroll
        for (int k2 = 0; k2 < 2; ++k2) {
            const float d = dst1[h * RTOT + b * NN + tid + 512 * k2];
            dstv2[tid + 512 * k2] = d;
            lm = fmaxf(lm, d);
        }
        if (tid < 128) srcv2[tid] = src1[h * RTOT + b * NN + i0 + tid];
#pragma unroll
        for (int o = 32; o > 0; o >>= 1) lm = fmaxf(lm, __shfl_xor(lm, o, 64));
        if (lane == 0) red8[wave] = lm;
        __syncthreads();
        float dmax = red8[0];
#pragma unroll
        for (int w = 1; w < 8; ++w) dmax = fmaxf(dmax, red8[w]);

        const int arow = tid >> 2, apart = tid & 3;           // 128 rows x 4 parts of 16
        const float si = srcv2[arow];
        float mrow = si + dmax;
        mrow = mrow >= 0.f ? mrow : ALPHA * mrow;             // per-row max (monotone leaky)
        float fsum = 0.f;

        const ushortT* Bbase = WhT + (size_t)(bh * DH) * NN;
        const int mg = wave >> 1, fg = wave & 1;
        f32x4 acc[2][4];
#pragma unroll
        for (int a = 0; a < 2; ++a)
#pragma unroll
            for (int c = 0; c < 4; ++c) acc[a][c] = (f32x4){0.f, 0.f, 0.f, 0.f};

#define STAGE2K(kt_, buf_)                                                                 \
        {                                                                                  \
            const int kt__ = (kt_);                                                        \
            ushortT* bdst = Bs2 + (buf_) * 128 * 64;                                       \
            _Pragma("unroll")                                                              \
            for (int half = 0; half < 2; ++half) {                                         \
                const int f = wave * 16 + half * 8 + (lane >> 3);                          \
                gload16(Bbase + (size_t)f * NN + kt__ * 64 + (((lane & 7) ^ (f & 7)) * 8), \
                        bdst + (wave * 16 + half * 8) * 64);                               \
            }                                                                              \
            const unsigned w0 = mask2[arow * 32 + kt__ * 2 + (apart >> 1)];                \
            const int bb = (apart & 1) * 16;                                               \
            union { ushortT u[16]; uint4 q[2]; } tw;                                       \
            _Pragma("unroll")                                                              \
            for (int e4 = 0; e4 < 4; ++e4) {                                               \
                const float4 dv = *(const float4*)&dstv2[kt__ * 64 + apart * 16 + e4 * 4]; \
                const float vv[4] = {dv.x, dv.y, dv.z, dv.w};                              \
                _Pragma("unroll")                                                          \
                for (int e = 0; e < 4; ++e) {                                              \
                    float v = si + vv[e];                                                  \
                    v = v >= 0.f ? v : ALPHA * v;                                          \
                    const unsigned bit = (w0 >> (bb + e4 * 4 + e)) & 1u;                   \
                    const float p = bit ? __expf(v - mrow) : 0.f;                          \
                    fsum += p;                                                             \
                    tw.u[e4 * 4 + e] = f2bf(p);                                            \
                }                                                                          \
            }                                                                              \
            const int c0 = (apart * 2) ^ (arow & 7), c1 = (apart * 2 + 1) ^ (arow & 7);    \
            ushortT* adst = As2 + (buf_) * 128 * 64 + arow * 64;                           \
            *(uint4*)&adst[c0 * 8] = tw.q[0];                                              \
            *(uint4*)&adst[c1 * 8] = tw.q[1];                                              \
        }

        STAGE2K(0, 0);
        for (int kt = 0; kt < 16; ++kt) {
            const int cb = kt & 1;
            __syncthreads();
            if (kt < 15) STAGE2K(kt + 1, cb ^ 1);
            const ushortT* Asb = As2 + cb * 128 * 64;
            const ushortT* Bsb = Bs2 + cb * 128 * 64;
#pragma unroll
            for (int ks = 0; ks < 2; ++ks) {
                bf16x8 afr[2];
#pragma unroll
                for (int ms = 0; ms < 2; ++ms) {
                    const int rowa = mg * 32 + ms * 16 + m16;
                    const int cla = (ks * 4 + quad) ^ (rowa & 7);
                    afr[ms] = *(const bf16x8*)&Asb[rowa * 64 + cla * 8];
                }
#pragma unroll
                for (int ff = 0; ff < 4; ++ff) {
                    const int rowb = fg * 64 + ff * 16 + m16;
                    const int clb = (ks * 4 + quad) ^ (rowb & 7);
                    const bf16x8 bfr = *(const bf16x8*)&Bsb[rowb * 64 + clb * 8];
#pragma unroll
                    for (int ms = 0; ms < 2; ++ms)
                        acc[ms][ff] = __builtin_amdgcn_mfma_f32_16x16x32_bf16(afr[ms], bfr, acc[ms][ff], 0, 0, 0);
                }
            }
        }
#undef STAGE2K
#pragma unroll
        for (int o = 1; o < 4; o <<= 1) fsum += __shfl_xor(fsum, o, 64);
        if ((lane & 3) == 0) rowinv2[arow] = 1.f / fsum;
        __syncthreads();
#pragma unroll
        for (int ms = 0; ms < 2; ++ms) {
            float rv[4];
#pragma unroll
            for (int reg = 0; reg < 4; ++reg) rv[reg] = rowinv2[mg * 32 + ms * 16 + quad * 4 + reg];
#pragma unroll
            for (int ff = 0; ff < 4; ++ff) {
                const int f = h * DH + fg * 64 + ff * 16 + m16;
#pragma unroll
                for (int reg = 0; reg < 4; ++reg) {
                    const int i = i0 + mg * 32 + ms * 16 + quad * 4 + reg;
                    xcat[(size_t)(b * NN + i) * FCAT + f] = f2bf(acc[ms][ff][reg] * rv[reg]);
                }
            }
        }
    }
    grid.sync();

    // ---------------- S3: wh2 GEMM (tile M=32, F=64, K=512), full-A resident ----------------
    {
        ushortT* As3 = (ushortT*)smem;                        // [8 kt][32*64] 32 KB
        ushortT* B3h = As3 + 8 * 32 * 64;                     // [2][64*64] 16 KB
        ushortT* B3l = B3h + 2 * 64 * 64;                     // [2][64*64] 16 KB
        float* sred3 = (float*)(smem + 65536);                // [8][16]
        float* dred3 = sred3 + 128;
        const int r0 = bx * 32, b = r0 >> 10, jr = r0 & 1023;
        const int mfrag = wave >> 2, fq = wave & 3;           // 2 x 4 wave-tiles of 16x16

        // stage full A (32 rows x 512 k): wave w stages kt=w subtile
#pragma unroll
        for (int half = 0; half < 4; ++half) {
            const int row = half * 8 + (lane >> 3);
            const int sc = (lane & 7) ^ (row & 7);
            gload16(xcat + (size_t)(r0 + row) * FCAT + wave * 64 + sc * 8, As3 + wave * 2048 + half * 512);
        }
#define S3B(kt_, buf_)                                                                     \
        {                                                                                  \
            const int f = wave * 8 + (lane >> 3);                                          \
            const int sc = (lane & 7) ^ (f & 7);                                           \
            gload16(WoTh + (size_t)f * FCAT + (kt_) * 64 + sc * 8, B3h + (buf_) * 4096 + wave * 512); \
            gload16(WoTl + (size_t)f * FCAT + (kt_) * 64 + sc * 8, B3l + (buf_) * 4096 + wave * 512); \
        }
        f32x4 acc3 = (f32x4){0.f, 0.f, 0.f, 0.f};
        S3B(0, 0);
        for (int kt = 0; kt < 8; ++kt) {
            const int cb = kt & 1;
            __syncthreads();
            if (kt < 7) S3B(kt + 1, cb ^ 1);
#pragma unroll
            for (int ks = 0; ks < 2; ++ks) {
                const int rowa = mfrag * 16 + m16;
                const int cla = (ks * 4 + quad) ^ (rowa & 7);
                const bf16x8 afr = *(const bf16x8*)&As3[kt * 2048 + rowa * 64 + cla * 8];
                const int rowb = fq * 16 + m16;
                const int clb = (ks * 4 + quad) ^ (rowb & 7);
                const bf16x8 b_h = *(const bf16x8*)&B3h[cb * 4096 + rowb * 64 + clb * 8];
                const bf16x8 b_l = *(const bf16x8*)&B3l[cb * 4096 + rowb * 64 + clb * 8];
                acc3 = __builtin_amdgcn_mfma_f32_16x16x32_bf16(afr, b_h, acc3, 0, 0, 0);
                acc3 = __builtin_amdgcn_mfma_f32_16x16x32_bf16(afr, b_l, acc3, 0, 0, 0);
            }
        }
#undef S3B
        // epilogue: Wh2T bf16 + fused src2/dst2 partials
        {
            const int f = fq * 16 + m16;
            const float a_s = aout[f], a_d = aout[DOUT + f];
            float sv[4], dv[4];
            union { ushortT u[4]; uint2 q; } tw;
#pragma unroll
            for (int reg = 0; reg < 4; ++reg) {
                const float v = acc3[reg];
                sv[reg] = v * a_s;
                dv[reg] = v * a_d;
                tw.u[reg] = f2bf(v);
            }
            *(uint2*)(Wh2T + ((size_t)(b * DOUT + f)) * NN + jr + mfrag * 16 + quad * 4) = tw.q;
#pragma unroll
            for (int reg = 0; reg < 4; ++reg) {
#pragma unroll
                for (int o = 1; o < 16; o <<= 1) {
                    sv[reg] += __shfl_xor(sv[reg], o, 64);
                    dv[reg] += __shfl_xor(dv[reg], o, 64);
                }
                if (m16 == 0) {
                    sred3[wave * 16 + quad * 4 + reg] = sv[reg];
                    dred3[wave * 16 + quad * 4 + reg] = dv[reg];
                }
            }
        }
        __syncthreads();
        if (tid < 32) {
            const int mf = tid >> 4, idx = tid & 15;
            float s = 0.f, d = 0.f;
#pragma unroll
            for (int q = 0; q < 4; ++q) {
                s += sred3[(mf * 4 + q) * 16 + idx];
                d += dred3[(mf * 4 + q) * 16 + idx];
            }
            src2[r0 + tid] = s;
            dst2[r0 + tid] = d;
        }
    }
    grid.sync();

    // ---------------- S4: attn2 + ELU + FC + ReLU (tile M=32, F=64, K=1024) ----------------
    {
        ushortT* As4 = (ushortT*)smem;                        // [2][32*64] 8 KB
        ushortT* Bs4 = As4 + 2 * 32 * 64;                     // [2][64*64] 16 KB
        ushortT* Wfh4 = Bs4 + 2 * 64 * 64;                    // [64*64] 8 KB
        ushortT* Wfl4 = Wfh4 + 64 * 64;                       // 8 KB
        unsigned* mask4 = (unsigned*)(smem + 40960);          // [1024] 4 KB
        float* dstv4 = (float*)(smem + 45056);                // [1024] 4 KB
        float* t2s = (float*)(smem + 49152);                  // [32*68] 8.5 KB
        float* srcv4 = (float*)(smem + 57856);                // [32]
        float* rowinv4 = srcv4 + 32;                          // [32]
        float* red8b = rowinv4 + 32;                          // [8]
        const int b = bx & 7, it = bx >> 3, i0 = it * 32;

        const unsigned* mbase = adjbit + (size_t)(b * NN + i0) * 32;
#pragma unroll
        for (int k2 = 0; k2 < 2; ++k2) mask4[tid + 512 * k2] = mbase[tid + 512 * k2];
        float lm = -INFINITY;
#pragma unroll
        for (int k2 = 0; k2 < 2; ++k2) {
            const float d = dst2[b * NN + tid + 512 * k2];
            dstv4[tid + 512 * k2] = d;
            lm = fmaxf(lm, d);
        }
        if (tid < 32) srcv4[tid] = src2[b * NN + i0 + tid];
        {   // stage Wf hi/lo: 8 elems per thread, [c][k] swizzled
            const int c = tid & 63, kc = wave * 8;
            union { ushortT u[8]; uint4 q; } th4, tl4;
#pragma unroll
            for (int e = 0; e < 8; ++e)
                split2(Wf[(size_t)(kc + e) * DOUT + c], th4.u[e], tl4.u[e]);
            const int ch = wave ^ (c & 7);
            *(uint4*)&Wfh4[c * 64 + ch * 8] = th4.q;
            *(uint4*)&Wfl4[c * 64 + ch * 8] = tl4.q;
        }
#pragma unroll
        for (int o = 32; o > 0; o >>= 1) lm = fmaxf(lm, __shfl_xor(lm, o, 64));
        if (lane == 0) red8b[wave] = lm;
        __syncthreads();
        float dmax = red8b[0];
#pragma unroll
        for (int w = 1; w < 8; ++w) dmax = fmaxf(dmax, red8b[w]);

        const int arow = tid >> 4, apart = tid & 15;          // 32 rows x 16 parts of 4
        const float si = srcv4[arow];
        float mrow = si + dmax;
        mrow = mrow >= 0.f ? mrow : ALPHA * mrow;
        float fsum = 0.f;

        const int mfrag = wave >> 2, fq = wave & 3;           // 2 x 4 wave-tiles of 16x16
        const ushortT* Bbase = Wh2T + (size_t)(b * DOUT) * NN;
        f32x4 acc4 = (f32x4){0.f, 0.f, 0.f, 0.f};

#define STAGE4K(kt_, buf_)                                                                 \
        {                                                                                  \
            const int kt__ = (kt_);                                                        \
            const int f = wave * 8 + (lane >> 3);                                          \
            gload16(Bbase + (size_t)f * NN + kt__ * 64 + (((lane & 7) ^ (f & 7)) * 8),     \
                    Bs4 + (buf_) * 4096 + wave * 512);                                     \
            const unsigned w0 = mask4[arow * 32 + kt__ * 2 + (apart >> 3)];                \
            const int bb = (apart & 7) * 4;                                                \
            union { ushortT u[4]; uint2 q; } tw;                                           \
            const float4 dv = *(const float4*)&dstv4[kt__ * 64 + apart * 4];               \
            const float vv[4] = {dv.x, dv.y, dv.z, dv.w};                                  \
            _Pragma("unroll")                                                              \
            for (int e = 0; e < 4; ++e) {                                                  \
                float v = si + vv[e];                                                      \
                v = v >= 0.f ? v : ALPHA * v;                                              \
                const unsigned bit = (w0 >> (bb + e)) & 1u;                                \
                const float p = bit ? __expf(v - mrow) : 0.f;                              \
                fsum += p;                                                                 \
                tw.u[e] = f2bf(p);                                                         \
            }                                                                              \
            *(uint2*)&As4[(buf_) * 2048 + arow * 64 + (((apart >> 1) ^ (arow & 7)) * 8) + (apart & 1) * 4] = tw.q; \
        }

        STAGE4K(0, 0);
        for (int kt = 0; kt < 16; ++kt) {
            const int cb = kt & 1;
            __syncthreads();
            if (kt < 15) STAGE4K(kt + 1, cb ^ 1);
#pragma unroll
            for (int ks = 0; ks < 2; ++ks) {
                const int rowa = mfrag * 16 + m16;
                const int cla = (ks * 4 + quad) ^ (rowa & 7);
                const bf16x8 afr = *(const bf16x8*)&As4[cb * 2048 + rowa * 64 + cla * 8];
                const int rowb = fq * 16 + m16;
                const int clb = (ks * 4 + quad) ^ (rowb & 7);
                const bf16x8 bfr = *(const bf16x8*)&Bs4[cb * 4096 + rowb * 64 + clb * 8];
                acc4 = __builtin_amdgcn_mfma_f32_16x16x32_bf16(afr, bfr, acc4, 0, 0, 0);
            }
        }
#undef STAGE4K
#pragma unroll
        for (int o = 1; o < 16; o <<= 1) fsum += __shfl_xor(fsum, o, 64);
        if ((lane & 15) == 0) rowinv4[arow] = 1.f / fsum;
        __syncthreads();
        // softmax scale + ELU -> t2s
#pragma unroll
        for (int reg = 0; reg < 4; ++reg) {
            const int row = mfrag * 16 + quad * 4 + reg;
            float v = acc4[reg] * rowinv4[row];
            v = v > 0.f ? v : (__expf(v) - 1.f);
            t2s[row * 68 + fq * 16 + m16] = v;
        }
        __syncthreads();
        // FC: out = relu(t2 @ Wf + bf)
        const int cc = fq * 16 + m16;
        f32x4 oacc;
        {
            const float bias = bfv[cc];
            oacc = (f32x4){bias, bias, bias, bias};
        }
#pragma unroll
        for (int ks = 0; ks < 2; ++ks) {
            const int rowa = mfrag * 16 + m16;
            const float4 fA = *(const float4*)&t2s[rowa * 68 + ks * 32 + quad * 8];
            const float4 fB = *(const float4*)&t2s[rowa * 68 + ks * 32 + quad * 8 + 4];
            union { ushortT u[8]; bf16x8 v; } a_h, a_l;
            const float av[8] = {fA.x, fA.y, fA.z, fA.w, fB.x, fB.y, fB.z, fB.w};
#pragma unroll
            for (int e = 0; e < 8; ++e) split2(av[e], a_h.u[e], a_l.u[e]);
            const int cl = (ks * 4 + quad) ^ (cc & 7);
            const bf16x8 b_h = *(const bf16x8*)&Wfh4[cc * 64 + cl * 8];
            const bf16x8 b_l = *(const bf16x8*)&Wfl4[cc * 64 + cl * 8];
            oacc = __builtin_amdgcn_mfma_f32_16x16x32_bf16(a_h.v, b_h, oacc, 0, 0, 0);
            oacc = __builtin_amdgcn_mfma_f32_16x16x32_bf16(a_h.v, b_l, oacc, 0, 0, 0);
            oacc = __builtin_amdgcn_mfma_f32_16x16x32_bf16(a_l.v, b_h, oacc, 0, 0, 0);
        }
#pragma unroll
        for (int reg = 0; reg < 4; ++reg) {
            const int i = i0 + mfrag * 16 + quad * 4 + reg;
            out[(size_t)(b * NN + i) * DOUT + cc] = fmaxf(oacc[reg], 0.f);
        }
    }
}

extern "C" void kernel_launch(void* const* d_in, const int* in_sizes, int n_in,
                              void* d_out, int out_size, void* d_ws, size_t ws_size,
                              hipStream_t stream) {
    const float* x   = (const float*)d_in[0];
    const int*   adj = (const int*)d_in[1];
    const float* Wh  = (const float*)d_in[2];
    const float* ah  = (const float*)d_in[3];
    const float* Wo  = (const float*)d_in[4];
    const float* ao  = (const float*)d_in[5];
    const float* Wf  = (const float*)d_in[6];
    const float* bf  = (const float*)d_in[7];
    float* out = (float*)d_out;

    float* ws    = (float*)d_ws;
    float* src1  = ws;                                 // 4*8192
    float* dst1  = src1 + NH * RTOT;                   // 4*8192
    float* src2  = dst1 + NH * RTOT;                   // 8192
    float* dst2  = src2 + RTOT;                        // 8192
    ushortT* WhT   = (ushortT*)(dst2 + RTOT);                // 8192*512 bf16
    ushortT* Wh2T  = WhT + (size_t)RTOT * FCAT;              // 8192*64
    ushortT* xcat  = Wh2T + (size_t)RTOT * DOUT;             // 8192*512
    ushortT* WbTh  = xcat + (size_t)RTOT * FCAT;             // 131072
    ushortT* WbTl  = WbTh + NH * DH * DIN;
    ushortT* WoTh  = WbTl + NH * DH * DIN;                   // 32768
    ushortT* WoTl  = WoTh + DOUT * FCAT;
    unsigned* adjbit = (unsigned*)(WoTl + DOUT * FCAT);      // 262144 words
    ushortT* xbh  = (ushortT*)(adjbit + (size_t)BSZ * NN * 32);  // 8192*256 bf16 hi
    ushortT* xbl  = xbh + (size_t)RTOT * DIN;                    // 8192*256 bf16 lo

    void* args[] = {
        (void*)&x, (void*)&adj, (void*)&Wh, (void*)&ah, (void*)&Wo, (void*)&ao,
        (void*)&Wf, (void*)&bf, (void*)&out,
        (void*)&xbh, (void*)&xbl, (void*)&WbTh, (void*)&WbTl,
        (void*)&WoTh, (void*)&WoTl, (void*)&adjbit,
        (void*)&WhT, (void*)&src1, (void*)&dst1,
        (void*)&xcat, (void*)&Wh2T, (void*)&src2, (void*)&dst2
    };
    hipLaunchCooperativeKernel((const void*)k_mega, dim3(256), dim3(512), args, 0, stream);
}

// Round 3
// 156.596 us; speedup vs baseline: 1.8228x; 1.8228x over previous
//
#include <hip/hip_runtime.h>
#include <hip/hip_bf16.h>

// Shapes (fixed by reference): B=8, N=1024, Din=256, H=4, Dh=128, Do=64
#define BSZ 8
#define NN 1024
#define DIN 256
#define NH 4
#define DH 128
#define DOUT 64
#define RTOT (BSZ*NN)          // 8192 rows total
#define FCAT (NH*DH)           // 512
#define ALPHA 0.2f
#define XBLK 1024              // prep blocks for x->bf16 hi/lo

typedef unsigned short ushortT;
typedef __attribute__((ext_vector_type(8))) short bf16x8;
typedef __attribute__((ext_vector_type(4))) float f32x4;

static __device__ __forceinline__ ushortT f2bf(float f) {
    __hip_bfloat16 h = __float2bfloat16(f);
    return *reinterpret_cast<ushortT*>(&h);
}
static __device__ __forceinline__ float bfu2f(ushortT u) {
    return __uint_as_float(((unsigned)u) << 16);
}
static __device__ __forceinline__ void split2(float v, ushortT& hi, ushortT& lo) {
    hi = f2bf(v);
    lo = f2bf(v - bfu2f(hi));
}
// async global->LDS, 16B per lane; LDS dest = base(wave-uniform) + lane*16
static __device__ __forceinline__ void gload16(const ushortT* g, ushortT* l) {
    __builtin_amdgcn_global_load_lds(
        (const __attribute__((address_space(1))) unsigned int*)(const void*)g,
        (__attribute__((address_space(3))) unsigned int*)(void*)l, 16, 0, 0);
}

// ============ k_prepw: x -> bf16 hi/lo (row-major) + weight transforms ============
__global__ __launch_bounds__(256) void k_prepw(const float* __restrict__ x,
                                               const float* __restrict__ W,
                                               const float* __restrict__ Wout,
                                               ushortT* __restrict__ xbh, ushortT* __restrict__ xbl,
                                               ushortT* __restrict__ WbTh, ushortT* __restrict__ WbTl,
                                               ushortT* __restrict__ WoTh, ushortT* __restrict__ WoTl) {
    const int bx = blockIdx.x;
    if (bx < XBLK) {
        const int g = bx * 256 + threadIdx.x;           // 262144 threads, 8 floats each
        const float4* p = (const float4*)x + (size_t)g * 2;
        union { ushortT u[8]; uint4 q; } th, tl;
#pragma unroll
        for (int e4 = 0; e4 < 2; ++e4) {
            const float4 v = p[e4];
            split2(v.x, th.u[e4 * 4 + 0], tl.u[e4 * 4 + 0]);
            split2(v.y, th.u[e4 * 4 + 1], tl.u[e4 * 4 + 1]);
            split2(v.z, th.u[e4 * 4 + 2], tl.u[e4 * 4 + 2]);
            split2(v.w, th.u[e4 * 4 + 3], tl.u[e4 * 4 + 3]);
        }
        ((uint4*)xbh)[g] = th.q;
        ((uint4*)xbl)[g] = tl.q;
        return;
    }
    const int g2 = (bx - XBLK) * 256 + threadIdx.x;
    if (g2 < NH * DH * DIN) {           // 131072
        const int h = g2 >> 15, f = (g2 >> 8) & 127, k = g2 & 255;
        const int kt = k >> 6, k64 = k & 63;
        const float v = W[(size_t)h * DIN * DH + (size_t)k * DH + f];
        ushortT hi, lo; split2(v, hi, lo);
        const int idx = ((h * 4 + kt) * 128 + f) * 64 + k64;
        WbTh[idx] = hi; WbTl[idx] = lo;
    } else {
        const int g3 = g2 - NH * DH * DIN;   // < 32768
        const int f = g3 >> 9, k = g3 & 511;
        const float v = Wout[(size_t)k * DOUT + f];
        ushortT hi, lo; split2(v, hi, lo);
        WoTh[g3] = hi; WoTl[g3] = lo;
    }
}

// ============ k_main: blocks 0..255 = wh1 MFMA GEMM; blocks 256..767 = adj bit-pack ============
__global__ __launch_bounds__(512) void k_main(const ushortT* __restrict__ xbh,
                                              const ushortT* __restrict__ xbl,
                                              const float* __restrict__ ah_,
                                              const ushortT* __restrict__ WbTh,
                                              const ushortT* __restrict__ WbTl,
                                              const int* __restrict__ adj,
                                              unsigned* __restrict__ adjbit,
                                              ushortT* __restrict__ WhT,
                                              float* __restrict__ src1,
                                              float* __restrict__ dst1) {
    __shared__ ushortT Ah[128 * 64], Al[128 * 64];    // 32 KB
    __shared__ ushortT Bh[128 * 64], Bl[128 * 64];    // 32 KB
    __shared__ float sred[8][32], dred[8][32];
    const int tid = threadIdx.x;
    if (blockIdx.x >= 256) {
        const int g = (blockIdx.x - 256) * 512 + tid;     // 262144 words
        const int row = g >> 5, w = g & 31;
        const int4* p = (const int4*)(adj + (size_t)row * NN + w * 32);
        unsigned m = 0;
#pragma unroll
        for (int q = 0; q < 8; ++q) {
            const int4 v = p[q];
            m |= (v.x > 0 ? 1u : 0u) << (q * 4 + 0);
            m |= (v.y > 0 ? 1u : 0u) << (q * 4 + 1);
            m |= (v.z > 0 ? 1u : 0u) << (q * 4 + 2);
            m |= (v.w > 0 ? 1u : 0u) << (q * 4 + 3);
        }
        adjbit[g] = m;
        return;
    }
    const int lane = tid & 63, wave = tid >> 6;
    const int h = blockIdx.x >> 6, mt = blockIdx.x & 63;
    const int r0 = mt * 128, b = r0 >> 10, jr = r0 & 1023;
    const int m16 = lane & 15, quad = lane >> 4;
    const int mg = wave >> 1, fg = wave & 1;
    f32x4 acc[2][4];
#pragma unroll
    for (int a = 0; a < 2; ++a)
#pragma unroll
        for (int c = 0; c < 4; ++c) acc[a][c] = (f32x4){0.f, 0.f, 0.f, 0.f};

    for (int kt = 0; kt < 4; ++kt) {
        __syncthreads();
        const ushortT* planeH = WbTh + (size_t)((h * 4 + kt) * 128) * 64;
        const ushortT* planeL = WbTl + (size_t)((h * 4 + kt) * 128) * 64;
#pragma unroll
        for (int half = 0; half < 2; ++half) {
            const int f = wave * 16 + half * 8 + (lane >> 3);
            const int sc = (lane & 7) ^ (f & 7);
            gload16(planeH + (size_t)f * 64 + sc * 8, Bh + (wave * 16 + half * 8) * 64);
            gload16(planeL + (size_t)f * 64 + sc * 8, Bl + (wave * 16 + half * 8) * 64);
        }
#pragma unroll
        for (int half = 0; half < 2; ++half) {
            const int r = wave * 16 + half * 8 + (lane >> 3);
            const int sc = (lane & 7) ^ (r & 7);
            gload16(xbh + (size_t)(r0 + r) * DIN + kt * 64 + sc * 8, Ah + (wave * 16 + half * 8) * 64);
            gload16(xbl + (size_t)(r0 + r) * DIN + kt * 64 + sc * 8, Al + (wave * 16 + half * 8) * 64);
        }
        __syncthreads();
#pragma unroll
        for (int ks = 0; ks < 2; ++ks) {
            bf16x8 a_h[2], a_l[2], b_h[4], b_l[4];
#pragma unroll
            for (int ms = 0; ms < 2; ++ms) {
                const int row = (mg * 2 + ms) * 16 + m16;
                const int cl = (ks * 4 + quad) ^ (row & 7);
                a_h[ms] = *(const bf16x8*)&Ah[row * 64 + cl * 8];
                a_l[ms] = *(const bf16x8*)&Al[row * 64 + cl * 8];
            }
#pragma unroll
            for (int fs = 0; fs < 4; ++fs) {
                const int row = (fg * 4 + fs) * 16 + m16;
                const int cl = (ks * 4 + quad) ^ (row & 7);
                b_h[fs] = *(const bf16x8*)&Bh[row * 64 + cl * 8];
                b_l[fs] = *(const bf16x8*)&Bl[row * 64 + cl * 8];
            }
#pragma unroll
            for (int ms = 0; ms < 2; ++ms)
#pragma unroll
                for (int fs = 0; fs < 4; ++fs) {
                    acc[ms][fs] = __builtin_amdgcn_mfma_f32_16x16x32_bf16(a_h[ms], b_h[fs], acc[ms][fs], 0, 0, 0);
                    acc[ms][fs] = __builtin_amdgcn_mfma_f32_16x16x32_bf16(a_h[ms], b_l[fs], acc[ms][fs], 0, 0, 0);
                    acc[ms][fs] = __builtin_amdgcn_mfma_f32_16x16x32_bf16(a_l[ms], b_h[fs], acc[ms][fs], 0, 0, 0);
                }
        }
    }
    float sacc[2][4] = {{0,0,0,0},{0,0,0,0}}, dacc[2][4] = {{0,0,0,0},{0,0,0,0}};
#pragma unroll
    for (int ms = 0; ms < 2; ++ms)
#pragma unroll
        for (int fs = 0; fs < 4; ++fs) {
            const int fl = (fg * 4 + fs) * 16 + m16;
            const float a_s = ah_[h * 2 * DH + fl];
            const float a_d = ah_[h * 2 * DH + DH + fl];
            union { ushortT u[4]; uint2 q; } tw;
#pragma unroll
            for (int reg = 0; reg < 4; ++reg) {
                const float v = acc[ms][fs][reg];
                sacc[ms][reg] += v * a_s;
                dacc[ms][reg] += v * a_d;
                tw.u[reg] = f2bf(v);
            }
            *(uint2*)(WhT + ((size_t)((b * NH + h) * DH + fl)) * NN + jr + (mg * 2 + ms) * 16 + quad * 4) = tw.q;
        }
#pragma unroll
    for (int ms = 0; ms < 2; ++ms) {
#pragma unroll
        for (int reg = 0; reg < 4; ++reg) {
            float s = sacc[ms][reg], d = dacc[ms][reg];
#pragma unroll
            for (int o = 8; o > 0; o >>= 1) {
                s += __shfl_xor(s, o, 64);
                d += __shfl_xor(d, o, 64);
            }
            if (m16 == 0) {
                sred[wave][ms * 16 + quad * 4 + reg] = s;
                dred[wave][ms * 16 + quad * 4 + reg] = d;
            }
        }
    }
    __syncthreads();
    if (tid < 128) {
        const int mgr = tid >> 5, idx = tid & 31;
        src1[h * RTOT + r0 + tid] = sred[mgr * 2][idx] + sred[mgr * 2 + 1][idx];
        dst1[h * RTOT + r0 + tid] = dred[mgr * 2][idx] + dred[mgr * 2 + 1][idx];
    }
}

// ============ k_attn1: fused single-pass softmax + PV (layer 1), M=64, direct-B ============
// grid 512 (bh = bx&31, it = bx>>5), 512 thr (8 waves), tile M=64, F=128, K=1024 (16 kt).
// B fragments (WhT, L2-resident) load global->VGPR, register-double-buffered (no Bs LDS):
// removes half the ds_read_b128 pressure (LDS port was ~5x oversubscribed vs MFMA) and
// drops LDS to ~29 KB. A (masked-exp P tile) stays LDS double-buffered, 1 barrier per kt.
__global__ __launch_bounds__(512) void k_attn1(const unsigned* __restrict__ adjbit,
                                               const ushortT* __restrict__ WhT,
                                               const float* __restrict__ src1,
                                               const float* __restrict__ dst1,
                                               ushortT* __restrict__ xcat) {
    __shared__ ushortT As[2][64 * 64];               // 16 KB
    __shared__ unsigned maskS[64 * 32];              // 8 KB
    __shared__ float dstv[NN];                       // 4 KB
    __shared__ float srcv[64], rowinv[64], red8[8];
    const int tid = threadIdx.x, lane = tid & 63, wave = tid >> 6;
    const int bh = blockIdx.x & 31, it = blockIdx.x >> 5;
    const int b = bh >> 2, h = bh & 3;
    const int i0 = it * 64;
    const int m16 = lane & 15, quad = lane >> 4;
    const int mg = wave >> 2, fg = wave & 3;         // mg: 32-row half, fg: 32-col group

    const unsigned* mbase = adjbit + (size_t)(b * NN + i0) * 32;
#pragma unroll
    for (int k2 = 0; k2 < 4; ++k2) maskS[tid + 512 * k2] = mbase[tid + 512 * k2];
    float lm = -INFINITY;
#pragma unroll
    for (int k2 = 0; k2 < 2; ++k2) {
        const float d = dst1[h * RTOT + b * NN + tid + 512 * k2];
        dstv[tid + 512 * k2] = d;
        lm = fmaxf(lm, d);
    }
    if (tid < 64) srcv[tid] = src1[h * RTOT + b * NN + i0 + tid];
#pragma unroll
    for (int o = 32; o > 0; o >>= 1) lm = fmaxf(lm, __shfl_xor(lm, o, 64));
    if (lane == 0) red8[wave] = lm;
    __syncthreads();
    float dmax = red8[0];
#pragma unroll
    for (int w = 1; w < 8; ++w) dmax = fmaxf(dmax, red8[w]);

    const int arow = tid >> 3, apart = tid & 7;      // 64 rows x 8 parts
    const float si = srcv[arow];
    float mrow = si + dmax;
    mrow = mrow >= 0.f ? mrow : ALPHA * mrow;        // per-row max (monotone leaky)
    float fsum = 0.f;

    const ushortT* Bbase = WhT + (size_t)(bh * DH) * NN;
    f32x4 acc[2][2];
#pragma unroll
    for (int a = 0; a < 2; ++a)
#pragma unroll
        for (int c = 0; c < 2; ++c) acc[a][c] = (f32x4){0.f, 0.f, 0.f, 0.f};

    // A-staging (masked exp -> As[buf]); buf is a compile-time literal at each use
#define STAGE_A(kt_, buf_)                                                                 \
    {                                                                                      \
        const int kt__ = (kt_);                                                            \
        const unsigned w0 = maskS[arow * 32 + kt__ * 2 + (apart >> 2)];                    \
        const int bb = (apart & 3) * 8;                                                    \
        union { ushortT u[8]; uint4 q; } tw;                                               \
        _Pragma("unroll")                                                                  \
        for (int e4 = 0; e4 < 2; ++e4) {                                                   \
            const float4 dv = *(const float4*)&dstv[kt__ * 64 + apart * 8 + e4 * 4];       \
            const float vv[4] = {dv.x, dv.y, dv.z, dv.w};                                  \
            _Pragma("unroll")                                                              \
            for (int e = 0; e < 4; ++e) {                                                  \
                float v = si + vv[e];                                                      \
                v = v >= 0.f ? v : ALPHA * v;                                              \
                const unsigned bit = (w0 >> (bb + e4 * 4 + e)) & 1u;                       \
                const float p = bit ? __expf(v - mrow) : 0.f;                              \
                fsum += p;                                                                 \
                tw.u[e4 * 4 + e] = f2bf(p);                                                \
            }                                                                              \
        }                                                                                  \
        *(uint4*)&As[(buf_)][arow * 64 + (apart ^ (arow & 7)) * 8] = tw.q;                 \
    }
    // B fragment loads: direct global->reg (same bits the old LDS path delivered)
#define LOADB(kt_, dst_)                                                                   \
    {                                                                                      \
        _Pragma("unroll")                                                                  \
        for (int ks = 0; ks < 2; ++ks)                                                     \
            _Pragma("unroll")                                                              \
            for (int ff = 0; ff < 2; ++ff)                                                 \
                dst_[ks][ff] = *(const bf16x8*)(Bbase +                                    \
                    (size_t)(fg * 32 + ff * 16 + m16) * NN + (kt_) * 64 + (ks * 4 + quad) * 8); \
    }
#define MFMA_STEP(buf_, bv_)                                                               \
    {                                                                                      \
        _Pragma("unroll")                                                                  \
        for (int ks = 0; ks < 2; ++ks) {                                                   \
            bf16x8 afr[2];                                                                 \
            _Pragma("unroll")                                                              \
            for (int ms = 0; ms < 2; ++ms) {                                               \
                const int rowa = mg * 32 + ms * 16 + m16;                                  \
                const int cla = (ks * 4 + quad) ^ (rowa & 7);                              \
                afr[ms] = *(const bf16x8*)&As[(buf_)][rowa * 64 + cla * 8];                \
            }                                                                              \
            _Pragma("unroll")                                                              \
            for (int ff = 0; ff < 2; ++ff)                                                 \
                _Pragma("unroll")                                                          \
                for (int ms = 0; ms < 2; ++ms)                                             \
                    acc[ms][ff] = __builtin_amdgcn_mfma_f32_16x16x32_bf16(afr[ms], bv_[ks][ff], acc[ms][ff], 0, 0, 0); \
        }                                                                                  \
    }

    bf16x8 b0v[2][2], b1v[2][2];
    LOADB(0, b0v);
    STAGE_A(0, 0);
    for (int kt = 0; kt < 16; kt += 2) {
        __syncthreads();                             // As[0] for kt ready; reads of As[1] done
        if (kt < 15) { LOADB(kt + 1, b1v); STAGE_A(kt + 1, 1); }
        MFMA_STEP(0, b0v);
        __syncthreads();                             // As[1] ready; reads of As[0] done
        if (kt < 14) { LOADB(kt + 2, b0v); STAGE_A(kt + 2, 0); }
        MFMA_STEP(1, b1v);
    }
#undef STAGE_A
#undef LOADB
#undef MFMA_STEP
#pragma unroll
    for (int o = 1; o < 8; o <<= 1) fsum += __shfl_xor(fsum, o, 64);
    if ((lane & 7) == 0) rowinv[arow] = 1.f / fsum;
    __syncthreads();
#pragma unroll
    for (int ms = 0; ms < 2; ++ms) {
        float rv[4];
#pragma unroll
        for (int reg = 0; reg < 4; ++reg) rv[reg] = rowinv[mg * 32 + ms * 16 + quad * 4 + reg];
#pragma unroll
        for (int ff = 0; ff < 2; ++ff) {
            const int f = h * DH + fg * 32 + ff * 16 + m16;
#pragma unroll
            for (int reg = 0; reg < 4; ++reg) {
                const int i = i0 + mg * 32 + ms * 16 + quad * 4 + reg;
                xcat[(size_t)(b * NN + i) * FCAT + f] = f2bf(acc[ms][ff][reg] * rv[reg]);
            }
        }
    }
}

// ============ k_wh2: Wh2 = xcat @ W_out, staged GEMM, fused Wh2T + src2/dst2 ============
// grid 256 (r0 = bx*32), 256 thr (4 waves), tile M=32, F=64, K=512 (8 kt)
__global__ __launch_bounds__(256) void k_wh2(const ushortT* __restrict__ xcat,
                                             const ushortT* __restrict__ WoTh,
                                             const ushortT* __restrict__ WoTl,
                                             const float* __restrict__ aout,
                                             ushortT* __restrict__ Wh2T,
                                             float* __restrict__ src2,
                                             float* __restrict__ dst2) {
    __shared__ ushortT As[32 * 64];                  // 4 KB
    __shared__ ushortT Bh[64 * 64], Bl[64 * 64];     // 16 KB
    __shared__ float sred[4][16], dred[4][16];
    const int tid = threadIdx.x, lane = tid & 63, wave = tid >> 6;
    const int r0 = blockIdx.x * 32;
    const int b = r0 >> 10, jr = r0 & 1023;
    const int m16 = lane & 15, quad = lane >> 4;
    const int mg = wave >> 1, fg = wave & 1;         // mg: row-frag 0..1, fg: f-half 0..1
    f32x4 acc[2] = {(f32x4){0.f,0.f,0.f,0.f}, (f32x4){0.f,0.f,0.f,0.f}};

    for (int kt = 0; kt < 8; ++kt) {
        __syncthreads();
        {   // A: 32 rows of xcat, wave covers 8 rows
            const int row = wave * 8 + (lane >> 3);
            const int sc = (lane & 7) ^ (row & 7);
            gload16(xcat + (size_t)(r0 + row) * FCAT + kt * 64 + sc * 8, As + wave * 8 * 64);
        }
#pragma unroll
        for (int half = 0; half < 2; ++half) {   // B: 64 f-rows, wave covers 16
            const int f = wave * 16 + half * 8 + (lane >> 3);
            const int sc = (lane & 7) ^ (f & 7);
            gload16(WoTh + (size_t)f * FCAT + kt * 64 + sc * 8, Bh + (wave * 16 + half * 8) * 64);
            gload16(WoTl + (size_t)f * FCAT + kt * 64 + sc * 8, Bl + (wave * 16 + half * 8) * 64);
        }
        __syncthreads();
#pragma unroll
        for (int ks = 0; ks < 2; ++ks) {
            const int rowa = mg * 16 + m16;
            const int cla = (ks * 4 + quad) ^ (rowa & 7);
            const bf16x8 afr = *(const bf16x8*)&As[rowa * 64 + cla * 8];
#pragma unroll
            for (int ff = 0; ff < 2; ++ff) {
                const int rowb = fg * 32 + ff * 16 + m16;
                const int clb = (ks * 4 + quad) ^ (rowb & 7);
                const bf16x8 b_h = *(const bf16x8*)&Bh[rowb * 64 + clb * 8];
                const bf16x8 b_l = *(const bf16x8*)&Bl[rowb * 64 + clb * 8];
                acc[ff] = __builtin_amdgcn_mfma_f32_16x16x32_bf16(afr, b_h, acc[ff], 0, 0, 0);
                acc[ff] = __builtin_amdgcn_mfma_f32_16x16x32_bf16(afr, b_l, acc[ff], 0, 0, 0);
            }
        }
    }
    // epilogue: Wh2T bf16 + fused src2/dst2 partials
    float sv[4] = {0, 0, 0, 0}, dv[4] = {0, 0, 0, 0};
#pragma unroll
    for (int ff = 0; ff < 2; ++ff) {
        const int f = fg * 32 + ff * 16 + m16;
        const float a_s = aout[f], a_d = aout[DOUT + f];
        union { ushortT u[4]; uint2 q; } tw;
#pragma unroll
        for (int reg = 0; reg < 4; ++reg) {
            const float v = acc[ff][reg];
            sv[reg] += v * a_s;
            dv[reg] += v * a_d;
            tw.u[reg] = f2bf(v);
        }
        *(uint2*)(Wh2T + ((size_t)(b * DOUT + f)) * NN + jr + mg * 16 + quad * 4) = tw.q;
    }
#pragma unroll
    for (int reg = 0; reg < 4; ++reg) {
#pragma unroll
        for (int o = 8; o > 0; o >>= 1) {
            sv[reg] += __shfl_xor(sv[reg], o, 64);
            dv[reg] += __shfl_xor(dv[reg], o, 64);
        }
        if (m16 == 0) { sred[wave][quad * 4 + reg] = sv[reg]; dred[wave][quad * 4 + reg] = dv[reg]; }
    }
    __syncthreads();
    if (tid < 32) {
        const int mgr = tid >> 4, idx = tid & 15;
        src2[r0 + tid] = sred[mgr * 2][idx] + sred[mgr * 2 + 1][idx];
        dst2[r0 + tid] = dred[mgr * 2][idx] + dred[mgr * 2 + 1][idx];
    }
}

// ============ k_attn2: softmax + PV + ELU + FC + ReLU (layer 2), 8 waves, direct-B ============
// grid 256 (b = bx&7, it = bx>>3), 512 thr, tile M=32, F=64, K=1024 (16 kt).
// Same direct-B transform as k_attn1 (Wh2T is L2-resident); 8 waves doubles TLP at 1 blk/CU.
__global__ __launch_bounds__(512) void k_attn2(const unsigned* __restrict__ adjbit,
                                               const ushortT* __restrict__ Wh2T,
                                               const float* __restrict__ src2,
                                               const float* __restrict__ dst2,
                                               const float* __restrict__ Wf,
                                               const float* __restrict__ bfv,
                                               float* __restrict__ out) {
    __shared__ ushortT As[2][32 * 64];              // 8 KB
    __shared__ ushortT Wfh[64 * 64], Wfl[64 * 64];  // 16 KB
    __shared__ unsigned maskS[32 * 32];             // 4 KB
    __shared__ float dstv[NN];                      // 4 KB
    __shared__ float t2s[32 * 68];                  // 8.5 KB
    __shared__ float srcv[32], rowinv[32], red8[8];
    const int tid = threadIdx.x, lane = tid & 63, wave = tid >> 6;
    const int b = blockIdx.x & 7, it = blockIdx.x >> 3;
    const int i0 = it * 32;
    const int m16 = lane & 15, quad = lane >> 4;

    const unsigned* mbase = adjbit + (size_t)(b * NN + i0) * 32;
#pragma unroll
    for (int k2 = 0; k2 < 2; ++k2) maskS[tid + 512 * k2] = mbase[tid + 512 * k2];
    float lm = -INFINITY;
#pragma unroll
    for (int k2 = 0; k2 < 2; ++k2) {
        const float d = dst2[b * NN + tid + 512 * k2];
        dstv[tid + 512 * k2] = d;
        lm = fmaxf(lm, d);
    }
    if (tid < 32) srcv[tid] = src2[b * NN + i0 + tid];
    {   // stage Wf hi/lo: 8 elems per thread, [c][k] swizzled
        const int c = tid & 63, kc = wave * 8;
        union { ushortT u[8]; uint4 q; } th4, tl4;
#pragma unroll
        for (int e = 0; e < 8; ++e)
            split2(Wf[(size_t)(kc + e) * DOUT + c], th4.u[e], tl4.u[e]);
        const int ch = wave ^ (c & 7);
        *(uint4*)&Wfh[c * 64 + ch * 8] = th4.q;
        *(uint4*)&Wfl[c * 64 + ch * 8] = tl4.q;
    }
#pragma unroll
    for (int o = 32; o > 0; o >>= 1) lm = fmaxf(lm, __shfl_xor(lm, o, 64));
    if (lane == 0) red8[wave] = lm;
    __syncthreads();
    float dmax = red8[0];
#pragma unroll
    for (int w = 1; w < 8; ++w) dmax = fmaxf(dmax, red8[w]);

    const int arow = tid >> 4, apart = tid & 15;     // 32 rows x 16 parts of 4
    const float si = srcv[arow];
    float mrow = si + dmax;
    mrow = mrow >= 0.f ? mrow : ALPHA * mrow;
    float fsum = 0.f;

    const int mfrag = wave >> 2, fq = wave & 3;      // 2 x 4 wave-tiles of 16x16
    const ushortT* Bbase = Wh2T + (size_t)(b * DOUT) * NN;
    f32x4 acc4 = (f32x4){0.f, 0.f, 0.f, 0.f};

#define STAGE_A2(kt_, buf_)                                                                \
    {                                                                                      \
        const int kt__ = (kt_);                                                            \
        const unsigned w0 = maskS[arow * 32 + kt__ * 2 + (apart >> 3)];                    \
        const int bb = (apart & 7) * 4;                                                    \
        union { ushortT u[4]; uint2 q; } tw;                                               \
        const float4 dv = *(const float4*)&dstv[kt__ * 64 + apart * 4];                    \
        const float vv[4] = {dv.x, dv.y, dv.z, dv.w};                                      \
        _Pragma("unroll")                                                                  \
        for (int e = 0; e < 4; ++e) {                                                      \
            float v = si + vv[e];                                                          \
            v = v >= 0.f ? v : ALPHA * v;                                                  \
            const unsigned bit = (w0 >> (bb + e)) & 1u;                                    \
            const float p = bit ? __expf(v - mrow) : 0.f;                                  \
            fsum += p;                                                                     \
            tw.u[e] = f2bf(p);                                                             \
        }                                                                                  \
        *(uint2*)&As[(buf_)][arow * 64 + (((apart >> 1) ^ (arow & 7)) * 8) + (apart & 1) * 4] = tw.q; \
    }
#define LOADB2(kt_, dst_)                                                                  \
    {                                                                                      \
        _Pragma("unroll")                                                                  \
        for (int ks = 0; ks < 2; ++ks)                                                     \
            dst_[ks] = *(const bf16x8*)(Bbase +                                            \
                (size_t)(fq * 16 + m16) * NN + (kt_) * 64 + (ks * 4 + quad) * 8);          \
    }
#define MFMA_STEP2(buf_, bv_)                                                              \
    {                                                                                      \
        _Pragma("unroll")                                                                  \
        for (int ks = 0; ks < 2; ++ks) {                                                   \
            const int rowa = mfrag * 16 + m16;                                             \
            const int cla = (ks * 4 + quad) ^ (rowa & 7);                                  \
            const bf16x8 afr = *(const bf16x8*)&As[(buf_)][rowa * 64 + cla * 8];           \
            acc4 = __builtin_amdgcn_mfma_f32_16x16x32_bf16(afr, bv_[ks], acc4, 0, 0, 0);   \
        }                                                                                  \
    }

    bf16x8 b0v[2], b1v[2];
    LOADB2(0, b0v);
    STAGE_A2(0, 0);
    for (int kt = 0; kt < 16; kt += 2) {
        __syncthreads();
        if (kt < 15) { LOADB2(kt + 1, b1v); STAGE_A2(kt + 1, 1); }
        MFMA_STEP2(0, b0v);
        __syncthreads();
        if (kt < 14) { LOADB2(kt + 2, b0v); STAGE_A2(kt + 2, 0); }
        MFMA_STEP2(1, b1v);
    }
#undef STAGE_A2
#undef LOADB2
#undef MFMA_STEP2
#pragma unroll
    for (int o = 1; o < 16; o <<= 1) fsum += __shfl_xor(fsum, o, 64);
    if ((lane & 15) == 0) rowinv[arow] = 1.f / fsum;
    __syncthreads();
    // softmax scale + ELU -> t2s
#pragma unroll
    for (int reg = 0; reg < 4; ++reg) {
        const int row = mfrag * 16 + quad * 4 + reg;
        float v = acc4[reg] * rowinv[row];
        v = v > 0.f ? v : (__expf(v) - 1.f);
        t2s[row * 68 + fq * 16 + m16] = v;
    }
    __syncthreads();
    // FC: out = relu(t2 @ Wf + bf)
    const int cc = fq * 16 + m16;
    f32x4 oacc;
    {
        const float bias = bfv[cc];
        oacc = (f32x4){bias, bias, bias, bias};
    }
#pragma unroll
    for (int ks = 0; ks < 2; ++ks) {
        const int rowa = mfrag * 16 + m16;
        const float4 fA = *(const float4*)&t2s[rowa * 68 + ks * 32 + quad * 8];
        const float4 fB = *(const float4*)&t2s[rowa * 68 + ks * 32 + quad * 8 + 4];
        union { ushortT u[8]; bf16x8 v; } a_h, a_l;
        const float av[8] = {fA.x, fA.y, fA.z, fA.w, fB.x, fB.y, fB.z, fB.w};
#pragma unroll
        for (int e = 0; e < 8; ++e) split2(av[e], a_h.u[e], a_l.u[e]);
        const int cl = (ks * 4 + quad) ^ (cc & 7);
        const bf16x8 b_h = *(const bf16x8*)&Wfh[cc * 64 + cl * 8];
        const bf16x8 b_l = *(const bf16x8*)&Wfl[cc * 64 + cl * 8];
        oacc = __builtin_amdgcn_mfma_f32_16x16x32_bf16(a_h.v, b_h, oacc, 0, 0, 0);
        oacc = __builtin_amdgcn_mfma_f32_16x16x32_bf16(a_h.v, b_l, oacc, 0, 0, 0);
        oacc = __builtin_amdgcn_mfma_f32_16x16x32_bf16(a_l.v, b_h, oacc, 0, 0, 0);
    }
#pragma unroll
    for (int reg = 0; reg < 4; ++reg) {
        const int i = i0 + mfrag * 16 + quad * 4 + reg;
        out[(size_t)(b * NN + i) * DOUT + cc] = fmaxf(oacc[reg], 0.f);
    }
}

extern "C" void kernel_launch(void* const* d_in, const int* in_sizes, int n_in,
                              void* d_out, int out_size, void* d_ws, size_t ws_size,
                              hipStream_t stream) {
    const float* x   = (const float*)d_in[0];
    const int*   adj = (const int*)d_in[1];
    const float* Wh  = (const float*)d_in[2];
    const float* ah  = (const float*)d_in[3];
    const float* Wo  = (const float*)d_in[4];
    const float* ao  = (const float*)d_in[5];
    const float* Wf  = (const float*)d_in[6];
    const float* bf  = (const float*)d_in[7];
    float* out = (float*)d_out;

    float* ws    = (float*)d_ws;
    float* src1  = ws;                                 // 4*8192
    float* dst1  = src1 + NH * RTOT;                   // 4*8192
    float* src2  = dst1 + NH * RTOT;                   // 8192
    float* dst2  = src2 + RTOT;                        // 8192
    ushortT* WhT   = (ushortT*)(dst2 + RTOT);                // 8192*512 bf16
    ushortT* Wh2T  = WhT + (size_t)RTOT * FCAT;              // 8192*64
    ushortT* xcat  = Wh2T + (size_t)RTOT * DOUT;             // 8192*512
    ushortT* WbTh  = xcat + (size_t)RTOT * FCAT;             // 131072
    ushortT* WbTl  = WbTh + NH * DH * DIN;
    ushortT* WoTh  = WbTl + NH * DH * DIN;                   // 32768
    ushortT* WoTl  = WoTh + DOUT * FCAT;
    unsigned* adjbit = (unsigned*)(WoTl + DOUT * FCAT);      // 262144 words
    ushortT* xbh  = (ushortT*)(adjbit + (size_t)BSZ * NN * 32);  // 8192*256 bf16 hi
    ushortT* xbl  = xbh + (size_t)RTOT * DIN;                    // 8192*256 bf16 lo

    hipLaunchKernelGGL(k_prepw, dim3(XBLK + (NH * DH * DIN + DOUT * FCAT) / 256), dim3(256), 0, stream,
                       x, Wh, Wo, xbh, xbl, WbTh, WbTl, WoTh, WoTl);
    hipLaunchKernelGGL(k_main,  dim3(768), dim3(512), 0, stream,
                       xbh, xbl, ah, WbTh, WbTl, adj, adjbit, WhT, src1, dst1);
    hipLaunchKernelGGL(k_attn1, dim3(512), dim3(512), 0, stream,
                       adjbit, WhT, src1, dst1, xcat);
    hipLaunchKernelGGL(k_wh2,   dim3(256), dim3(256), 0, stream,
                       xcat, WoTh, WoTl, ao, Wh2T, src2, dst2);
    hipLaunchKernelGGL(k_attn2, dim3(256), dim3(512), 0, stream,
                       adjbit, Wh2T, src2, dst2, Wf, bf, out);
}

// Round 4
// 146.794 us; speedup vs baseline: 1.9445x; 1.0668x over previous
//
#include <hip/hip_runtime.h>
#include <hip/hip_bf16.h>

// Shapes (fixed by reference): B=8, N=1024, Din=256, H=4, Dh=128, Do=64
#define BSZ 8
#define NN 1024
#define DIN 256
#define NH 4
#define DH 128
#define DOUT 64
#define RTOT (BSZ*NN)          // 8192 rows total
#define FCAT (NH*DH)           // 512
#define ALPHA 0.2f
#define XBLK 1024              // prep blocks for x->bf16 hi/lo

typedef unsigned short ushortT;
typedef __attribute__((ext_vector_type(8))) short bf16x8;
typedef __attribute__((ext_vector_type(4))) float f32x4;

static __device__ __forceinline__ ushortT f2bf(float f) {
    __hip_bfloat16 h = __float2bfloat16(f);
    return *reinterpret_cast<ushortT*>(&h);
}
static __device__ __forceinline__ float bfu2f(ushortT u) {
    return __uint_as_float(((unsigned)u) << 16);
}
static __device__ __forceinline__ void split2(float v, ushortT& hi, ushortT& lo) {
    hi = f2bf(v);
    lo = f2bf(v - bfu2f(hi));
}
// async global->LDS, 16B per lane; LDS dest = base(wave-uniform) + lane*16
static __device__ __forceinline__ void gload16(const ushortT* g, ushortT* l) {
    __builtin_amdgcn_global_load_lds(
        (const __attribute__((address_space(1))) unsigned int*)(const void*)g,
        (__attribute__((address_space(3))) unsigned int*)(void*)l, 16, 0, 0);
}

// ============ k_prepw: x -> bf16 hi/lo (row-major) + weight transforms ============
__global__ __launch_bounds__(256) void k_prepw(const float* __restrict__ x,
                                               const float* __restrict__ W,
                                               const float* __restrict__ Wout,
                                               ushortT* __restrict__ xbh, ushortT* __restrict__ xbl,
                                               ushortT* __restrict__ WbTh, ushortT* __restrict__ WbTl,
                                               ushortT* __restrict__ WoTh, ushortT* __restrict__ WoTl) {
    const int bx = blockIdx.x;
    if (bx < XBLK) {
        const int g = bx * 256 + threadIdx.x;           // 262144 threads, 8 floats each
        const float4* p = (const float4*)x + (size_t)g * 2;
        union { ushortT u[8]; uint4 q; } th, tl;
#pragma unroll
        for (int e4 = 0; e4 < 2; ++e4) {
            const float4 v = p[e4];
            split2(v.x, th.u[e4 * 4 + 0], tl.u[e4 * 4 + 0]);
            split2(v.y, th.u[e4 * 4 + 1], tl.u[e4 * 4 + 1]);
            split2(v.z, th.u[e4 * 4 + 2], tl.u[e4 * 4 + 2]);
            split2(v.w, th.u[e4 * 4 + 3], tl.u[e4 * 4 + 3]);
        }
        ((uint4*)xbh)[g] = th.q;
        ((uint4*)xbl)[g] = tl.q;
        return;
    }
    const int g2 = (bx - XBLK) * 256 + threadIdx.x;
    if (g2 < NH * DH * DIN) {           // 131072
        const int h = g2 >> 15, f = (g2 >> 8) & 127, k = g2 & 255;
        const int kt = k >> 6, k64 = k & 63;
        const float v = W[(size_t)h * DIN * DH + (size_t)k * DH + f];
        ushortT hi, lo; split2(v, hi, lo);
        const int idx = ((h * 4 + kt) * 128 + f) * 64 + k64;
        WbTh[idx] = hi; WbTl[idx] = lo;
    } else {
        const int g3 = g2 - NH * DH * DIN;   // < 32768
        const int f = g3 >> 9, k = g3 & 511;
        const float v = Wout[(size_t)k * DOUT + f];
        ushortT hi, lo; split2(v, hi, lo);
        WoTh[g3] = hi; WoTl[g3] = lo;
    }
}

// ============ k_main: blocks 0..255 = wh1 MFMA GEMM; blocks 256..767 = adj bit-pack ============
__global__ __launch_bounds__(512) void k_main(const ushortT* __restrict__ xbh,
                                              const ushortT* __restrict__ xbl,
                                              const float* __restrict__ ah_,
                                              const ushortT* __restrict__ WbTh,
                                              const ushortT* __restrict__ WbTl,
                                              const int* __restrict__ adj,
                                              unsigned* __restrict__ adjbit,
                                              ushortT* __restrict__ WhT,
                                              float* __restrict__ src1,
                                              float* __restrict__ dst1) {
    __shared__ ushortT Ah[128 * 64], Al[128 * 64];    // 32 KB
    __shared__ ushortT Bh[128 * 64], Bl[128 * 64];    // 32 KB
    __shared__ float sred[8][32], dred[8][32];
    const int tid = threadIdx.x;
    if (blockIdx.x >= 256) {
        const int g = (blockIdx.x - 256) * 512 + tid;     // 262144 words
        const int row = g >> 5, w = g & 31;
        const int4* p = (const int4*)(adj + (size_t)row * NN + w * 32);
        unsigned m = 0;
#pragma unroll
        for (int q = 0; q < 8; ++q) {
            const int4 v = p[q];
            m |= (v.x > 0 ? 1u : 0u) << (q * 4 + 0);
            m |= (v.y > 0 ? 1u : 0u) << (q * 4 + 1);
            m |= (v.z > 0 ? 1u : 0u) << (q * 4 + 2);
            m |= (v.w > 0 ? 1u : 0u) << (q * 4 + 3);
        }
        adjbit[g] = m;
        return;
    }
    const int lane = tid & 63, wave = tid >> 6;
    const int h = blockIdx.x >> 6, mt = blockIdx.x & 63;
    const int r0 = mt * 128, b = r0 >> 10, jr = r0 & 1023;
    const int m16 = lane & 15, quad = lane >> 4;
    const int mg = wave >> 1, fg = wave & 1;
    f32x4 acc[2][4];
#pragma unroll
    for (int a = 0; a < 2; ++a)
#pragma unroll
        for (int c = 0; c < 4; ++c) acc[a][c] = (f32x4){0.f, 0.f, 0.f, 0.f};

    for (int kt = 0; kt < 4; ++kt) {
        __syncthreads();
        const ushortT* planeH = WbTh + (size_t)((h * 4 + kt) * 128) * 64;
        const ushortT* planeL = WbTl + (size_t)((h * 4 + kt) * 128) * 64;
#pragma unroll
        for (int half = 0; half < 2; ++half) {
            const int f = wave * 16 + half * 8 + (lane >> 3);
            const int sc = (lane & 7) ^ (f & 7);
            gload16(planeH + (size_t)f * 64 + sc * 8, Bh + (wave * 16 + half * 8) * 64);
            gload16(planeL + (size_t)f * 64 + sc * 8, Bl + (wave * 16 + half * 8) * 64);
        }
#pragma unroll
        for (int half = 0; half < 2; ++half) {
            const int r = wave * 16 + half * 8 + (lane >> 3);
            const int sc = (lane & 7) ^ (r & 7);
            gload16(xbh + (size_t)(r0 + r) * DIN + kt * 64 + sc * 8, Ah + (wave * 16 + half * 8) * 64);
            gload16(xbl + (size_t)(r0 + r) * DIN + kt * 64 + sc * 8, Al + (wave * 16 + half * 8) * 64);
        }
        __syncthreads();
#pragma unroll
        for (int ks = 0; ks < 2; ++ks) {
            bf16x8 a_h[2], a_l[2], b_h[4], b_l[4];
#pragma unroll
            for (int ms = 0; ms < 2; ++ms) {
                const int row = (mg * 2 + ms) * 16 + m16;
                const int cl = (ks * 4 + quad) ^ (row & 7);
                a_h[ms] = *(const bf16x8*)&Ah[row * 64 + cl * 8];
                a_l[ms] = *(const bf16x8*)&Al[row * 64 + cl * 8];
            }
#pragma unroll
            for (int fs = 0; fs < 4; ++fs) {
                const int row = (fg * 4 + fs) * 16 + m16;
                const int cl = (ks * 4 + quad) ^ (row & 7);
                b_h[fs] = *(const bf16x8*)&Bh[row * 64 + cl * 8];
                b_l[fs] = *(const bf16x8*)&Bl[row * 64 + cl * 8];
            }
#pragma unroll
            for (int ms = 0; ms < 2; ++ms)
#pragma unroll
                for (int fs = 0; fs < 4; ++fs) {
                    acc[ms][fs] = __builtin_amdgcn_mfma_f32_16x16x32_bf16(a_h[ms], b_h[fs], acc[ms][fs], 0, 0, 0);
                    acc[ms][fs] = __builtin_amdgcn_mfma_f32_16x16x32_bf16(a_h[ms], b_l[fs], acc[ms][fs], 0, 0, 0);
                    acc[ms][fs] = __builtin_amdgcn_mfma_f32_16x16x32_bf16(a_l[ms], b_h[fs], acc[ms][fs], 0, 0, 0);
                }
        }
    }
    float sacc[2][4] = {{0,0,0,0},{0,0,0,0}}, dacc[2][4] = {{0,0,0,0},{0,0,0,0}};
#pragma unroll
    for (int ms = 0; ms < 2; ++ms)
#pragma unroll
        for (int fs = 0; fs < 4; ++fs) {
            const int fl = (fg * 4 + fs) * 16 + m16;
            const float a_s = ah_[h * 2 * DH + fl];
            const float a_d = ah_[h * 2 * DH + DH + fl];
            union { ushortT u[4]; uint2 q; } tw;
#pragma unroll
            for (int reg = 0; reg < 4; ++reg) {
                const float v = acc[ms][fs][reg];
                sacc[ms][reg] += v * a_s;
                dacc[ms][reg] += v * a_d;
                tw.u[reg] = f2bf(v);
            }
            *(uint2*)(WhT + ((size_t)((b * NH + h) * DH + fl)) * NN + jr + (mg * 2 + ms) * 16 + quad * 4) = tw.q;
        }
#pragma unroll
    for (int ms = 0; ms < 2; ++ms) {
#pragma unroll
        for (int reg = 0; reg < 4; ++reg) {
            float s = sacc[ms][reg], d = dacc[ms][reg];
#pragma unroll
            for (int o = 8; o > 0; o >>= 1) {
                s += __shfl_xor(s, o, 64);
                d += __shfl_xor(d, o, 64);
            }
            if (m16 == 0) {
                sred[wave][ms * 16 + quad * 4 + reg] = s;
                dred[wave][ms * 16 + quad * 4 + reg] = d;
            }
        }
    }
    __syncthreads();
    if (tid < 128) {
        const int mgr = tid >> 5, idx = tid & 31;
        src1[h * RTOT + r0 + tid] = sred[mgr * 2][idx] + sred[mgr * 2 + 1][idx];
        dst1[h * RTOT + r0 + tid] = dred[mgr * 2][idx] + dred[mgr * 2 + 1][idx];
    }
}

// ============ k_attn1: fused softmax + PV (layer 1), M=128, in-register A ============
// grid 256 (bh = bx&31, it = bx>>5), 512 thr (8 waves). Wave w owns rows i0+w*16..+15,
// all 128 F cols (acc = 8 x f32x4). The P tile (masked exp) is computed DIRECTLY in the
// MFMA A-fragment layout (row=lane&15, k=quad*8+e) — no LDS round-trip, no A barrier,
// zero redundancy. B (WhT) stays LDS double-buffered via global_load_lds, 1 barrier/kt;
// DMA for kt+1 issued before kt's compute so the barrier's vmcnt drain is hidden.
// maskS padded to stride 34 (stride 32 was a 16-way bank conflict on uniform-word reads).
__global__ __launch_bounds__(512, 2) void k_attn1(const unsigned* __restrict__ adjbit,
                                                  const ushortT* __restrict__ WhT,
                                                  const float* __restrict__ src1,
                                                  const float* __restrict__ dst1,
                                                  ushortT* __restrict__ xcat) {
    __shared__ ushortT Bs[2][128 * 64];              // 32 KB
    __shared__ unsigned maskS[128 * 34];             // 17 KB (padded stride)
    __shared__ float dstv[NN];                       // 4 KB
    __shared__ float rowinv[128], red8[8];
    const int tid = threadIdx.x, lane = tid & 63, wave = tid >> 6;
    const int bh = blockIdx.x & 31, it = blockIdx.x >> 5;
    const int b = bh >> 2, h = bh & 3;
    const int i0 = it * 128;
    const int m16 = lane & 15, quad = lane >> 4;
    const ushortT* Bbase = WhT + (size_t)(bh * DH) * NN;

#define STAGEB(kt_, buf_)                                                                  \
    {                                                                                      \
        _Pragma("unroll")                                                                  \
        for (int half = 0; half < 2; ++half) {                                             \
            const int f = wave * 16 + half * 8 + (lane >> 3);                              \
            gload16(Bbase + (size_t)f * NN + (kt_) * 64 + (((lane & 7) ^ (f & 7)) * 8),    \
                    &Bs[(buf_)][(wave * 16 + half * 8) * 64]);                             \
        }                                                                                  \
    }

    STAGEB(0, 0);                                    // DMA overlaps prologue staging
    {   // masks: 128 rows x 32 words -> stride-34 LDS
        const uint4* msrc = (const uint4*)(adjbit + (size_t)(b * NN + i0) * 32) + tid * 2;
        const uint4 w0 = msrc[0], w1 = msrc[1];
        unsigned* mdst = &maskS[(tid >> 2) * 34 + (tid & 3) * 8];
        *(uint2*)&mdst[0] = make_uint2(w0.x, w0.y);
        *(uint2*)&mdst[2] = make_uint2(w0.z, w0.w);
        *(uint2*)&mdst[4] = make_uint2(w1.x, w1.y);
        *(uint2*)&mdst[6] = make_uint2(w1.z, w1.w);
    }
    float lm = -INFINITY;
#pragma unroll
    for (int k2 = 0; k2 < 2; ++k2) {
        const float d = dst1[h * RTOT + b * NN + tid + 512 * k2];
        dstv[tid + 512 * k2] = d;
        lm = fmaxf(lm, d);
    }
    const float si = src1[h * RTOT + b * NN + i0 + wave * 16 + m16];
#pragma unroll
    for (int o = 32; o > 0; o >>= 1) lm = fmaxf(lm, __shfl_xor(lm, o, 64));
    if (lane == 0) red8[wave] = lm;
    __syncthreads();                                 // masks, dstv, red8, Bs[0] all ready
    float dmax = red8[0];
#pragma unroll
    for (int w = 1; w < 8; ++w) dmax = fmaxf(dmax, red8[w]);
    float mrow = si + dmax;
    mrow = mrow >= 0.f ? mrow : ALPHA * mrow;        // per-row max (monotone leaky)

    f32x4 acc[8];
#pragma unroll
    for (int c = 0; c < 8; ++c) acc[c] = (f32x4){0.f, 0.f, 0.f, 0.f};
    float fsum = 0.f;
    const int arow34 = (wave * 16 + m16) * 34;

#define KSTEP(kt_, buf_)                                                                   \
    {                                                                                      \
        _Pragma("unroll")                                                                  \
        for (int ks = 0; ks < 2; ++ks) {                                                   \
            const unsigned w0 = maskS[arow34 + (kt_) * 2 + ks];                            \
            const float4 d0 = *(const float4*)&dstv[(kt_) * 64 + ks * 32 + quad * 8];      \
            const float4 d1 = *(const float4*)&dstv[(kt_) * 64 + ks * 32 + quad * 8 + 4];  \
            const float dv[8] = {d0.x, d0.y, d0.z, d0.w, d1.x, d1.y, d1.z, d1.w};          \
            union { ushortT u[8]; bf16x8 v; } pa;                                          \
            _Pragma("unroll")                                                              \
            for (int e = 0; e < 8; ++e) {                                                  \
                float v = si + dv[e];                                                      \
                v = v >= 0.f ? v : ALPHA * v;                                              \
                const unsigned bit = (w0 >> (quad * 8 + e)) & 1u;                          \
                const float p = bit ? __expf(v - mrow) : 0.f;                              \
                fsum += p;                                                                 \
                pa.u[e] = f2bf(p);                                                         \
            }                                                                              \
            _Pragma("unroll")                                                              \
            for (int ff = 0; ff < 8; ++ff) {                                               \
                const int rowb = ff * 16 + m16;                                            \
                const bf16x8 bfr = *(const bf16x8*)&Bs[(buf_)][rowb * 64 +                 \
                    (((ks * 4 + quad) ^ (rowb & 7)) * 8)];                                 \
                acc[ff] = __builtin_amdgcn_mfma_f32_16x16x32_bf16(pa.v, bfr, acc[ff], 0, 0, 0); \
            }                                                                              \
        }                                                                                  \
    }

    for (int kt = 0; kt < 16; kt += 2) {
        if (kt < 15) STAGEB(kt + 1, 1);              // DMA next tile while computing current
        KSTEP(kt, 0);
        __syncthreads();                             // buf1 ready; buf0 free
        if (kt < 14) STAGEB(kt + 2, 0);
        KSTEP(kt + 1, 1);
        __syncthreads();
    }
#undef STAGEB
#undef KSTEP

    // row sums: lane's fsum covers row (wave*16+m16), k-quarter quad -> reduce across quads
    fsum += __shfl_xor(fsum, 16, 64);
    fsum += __shfl_xor(fsum, 32, 64);
    if (quad == 0) rowinv[wave * 16 + m16] = 1.f / fsum;
    __syncthreads();
    const float4 rq = *(const float4*)&rowinv[wave * 16 + quad * 4];
    const float rv[4] = {rq.x, rq.y, rq.z, rq.w};
#pragma unroll
    for (int ff = 0; ff < 8; ++ff) {
        const int f = h * DH + ff * 16 + m16;
        ushortT* xc = xcat + (size_t)(b * NN + i0 + wave * 16 + quad * 4) * FCAT + f;
#pragma unroll
        for (int reg = 0; reg < 4; ++reg)
            xc[(size_t)reg * FCAT] = f2bf(acc[ff][reg] * rv[reg]);
    }
}

// ============ k_wh2: Wh2 = xcat @ W_out, staged GEMM, fused Wh2T + src2/dst2 ============
// grid 256 (r0 = bx*32), 256 thr (4 waves), tile M=32, F=64, K=512 (8 kt)
__global__ __launch_bounds__(256) void k_wh2(const ushortT* __restrict__ xcat,
                                             const ushortT* __restrict__ WoTh,
                                             const ushortT* __restrict__ WoTl,
                                             const float* __restrict__ aout,
                                             ushortT* __restrict__ Wh2T,
                                             float* __restrict__ src2,
                                             float* __restrict__ dst2) {
    __shared__ ushortT As[32 * 64];                  // 4 KB
    __shared__ ushortT Bh[64 * 64], Bl[64 * 64];     // 16 KB
    __shared__ float sred[4][16], dred[4][16];
    const int tid = threadIdx.x, lane = tid & 63, wave = tid >> 6;
    const int r0 = blockIdx.x * 32;
    const int b = r0 >> 10, jr = r0 & 1023;
    const int m16 = lane & 15, quad = lane >> 4;
    const int mg = wave >> 1, fg = wave & 1;         // mg: row-frag 0..1, fg: f-half 0..1
    f32x4 acc[2] = {(f32x4){0.f,0.f,0.f,0.f}, (f32x4){0.f,0.f,0.f,0.f}};

    for (int kt = 0; kt < 8; ++kt) {
        __syncthreads();
        {   // A: 32 rows of xcat, wave covers 8 rows
            const int row = wave * 8 + (lane >> 3);
            const int sc = (lane & 7) ^ (row & 7);
            gload16(xcat + (size_t)(r0 + row) * FCAT + kt * 64 + sc * 8, As + wave * 8 * 64);
        }
#pragma unroll
        for (int half = 0; half < 2; ++half) {   // B: 64 f-rows, wave covers 16
            const int f = wave * 16 + half * 8 + (lane >> 3);
            const int sc = (lane & 7) ^ (f & 7);
            gload16(WoTh + (size_t)f * FCAT + kt * 64 + sc * 8, Bh + (wave * 16 + half * 8) * 64);
            gload16(WoTl + (size_t)f * FCAT + kt * 64 + sc * 8, Bl + (wave * 16 + half * 8) * 64);
        }
        __syncthreads();
#pragma unroll
        for (int ks = 0; ks < 2; ++ks) {
            const int rowa = mg * 16 + m16;
            const int cla = (ks * 4 + quad) ^ (rowa & 7);
            const bf16x8 afr = *(const bf16x8*)&As[rowa * 64 + cla * 8];
#pragma unroll
            for (int ff = 0; ff < 2; ++ff) {
                const int rowb = fg * 32 + ff * 16 + m16;
                const int clb = (ks * 4 + quad) ^ (rowb & 7);
                const bf16x8 b_h = *(const bf16x8*)&Bh[rowb * 64 + clb * 8];
                const bf16x8 b_l = *(const bf16x8*)&Bl[rowb * 64 + clb * 8];
                acc[ff] = __builtin_amdgcn_mfma_f32_16x16x32_bf16(afr, b_h, acc[ff], 0, 0, 0);
                acc[ff] = __builtin_amdgcn_mfma_f32_16x16x32_bf16(afr, b_l, acc[ff], 0, 0, 0);
            }
        }
    }
    // epilogue: Wh2T bf16 + fused src2/dst2 partials
    float sv[4] = {0, 0, 0, 0}, dv[4] = {0, 0, 0, 0};
#pragma unroll
    for (int ff = 0; ff < 2; ++ff) {
        const int f = fg * 32 + ff * 16 + m16;
        const float a_s = aout[f], a_d = aout[DOUT + f];
        union { ushortT u[4]; uint2 q; } tw;
#pragma unroll
        for (int reg = 0; reg < 4; ++reg) {
            const float v = acc[ff][reg];
            sv[reg] += v * a_s;
            dv[reg] += v * a_d;
            tw.u[reg] = f2bf(v);
        }
        *(uint2*)(Wh2T + ((size_t)(b * DOUT + f)) * NN + jr + mg * 16 + quad * 4) = tw.q;
    }
#pragma unroll
    for (int reg = 0; reg < 4; ++reg) {
#pragma unroll
        for (int o = 8; o > 0; o >>= 1) {
            sv[reg] += __shfl_xor(sv[reg], o, 64);
            dv[reg] += __shfl_xor(dv[reg], o, 64);
        }
        if (m16 == 0) { sred[wave][quad * 4 + reg] = sv[reg]; dred[wave][quad * 4 + reg] = dv[reg]; }
    }
    __syncthreads();
    if (tid < 32) {
        const int mgr = tid >> 4, idx = tid & 15;
        src2[r0 + tid] = sred[mgr * 2][idx] + sred[mgr * 2 + 1][idx];
        dst2[r0 + tid] = dred[mgr * 2][idx] + dred[mgr * 2 + 1][idx];
    }
}

// ============ k_attn2: softmax + PV + ELU + FC + ReLU (layer 2), 8 waves, direct-B ============
// grid 256 (b = bx&7, it = bx>>3), 512 thr, tile M=32, F=64, K=1024 (16 kt).
__global__ __launch_bounds__(512) void k_attn2(const unsigned* __restrict__ adjbit,
                                               const ushortT* __restrict__ Wh2T,
                                               const float* __restrict__ src2,
                                               const float* __restrict__ dst2,
                                               const float* __restrict__ Wf,
                                               const float* __restrict__ bfv,
                                               float* __restrict__ out) {
    __shared__ ushortT As[2][32 * 64];              // 8 KB
    __shared__ ushortT Wfh[64 * 64], Wfl[64 * 64];  // 16 KB
    __shared__ unsigned maskS[32 * 32];             // 4 KB
    __shared__ float dstv[NN];                      // 4 KB
    __shared__ float t2s[32 * 68];                  // 8.5 KB
    __shared__ float srcv[32], rowinv[32], red8[8];
    const int tid = threadIdx.x, lane = tid & 63, wave = tid >> 6;
    const int b = blockIdx.x & 7, it = blockIdx.x >> 3;
    const int i0 = it * 32;
    const int m16 = lane & 15, quad = lane >> 4;

    const unsigned* mbase = adjbit + (size_t)(b * NN + i0) * 32;
#pragma unroll
    for (int k2 = 0; k2 < 2; ++k2) maskS[tid + 512 * k2] = mbase[tid + 512 * k2];
    float lm = -INFINITY;
#pragma unroll
    for (int k2 = 0; k2 < 2; ++k2) {
        const float d = dst2[b * NN + tid + 512 * k2];
        dstv[tid + 512 * k2] = d;
        lm = fmaxf(lm, d);
    }
    if (tid < 32) srcv[tid] = src2[b * NN + i0 + tid];
    {   // stage Wf hi/lo: 8 elems per thread, [c][k] swizzled
        const int c = tid & 63, kc = wave * 8;
        union { ushortT u[8]; uint4 q; } th4, tl4;
#pragma unroll
        for (int e = 0; e < 8; ++e)
            split2(Wf[(size_t)(kc + e) * DOUT + c], th4.u[e], tl4.u[e]);
        const int ch = wave ^ (c & 7);
        *(uint4*)&Wfh[c * 64 + ch * 8] = th4.q;
        *(uint4*)&Wfl[c * 64 + ch * 8] = tl4.q;
    }
#pragma unroll
    for (int o = 32; o > 0; o >>= 1) lm = fmaxf(lm, __shfl_xor(lm, o, 64));
    if (lane == 0) red8[wave] = lm;
    __syncthreads();
    float dmax = red8[0];
#pragma unroll
    for (int w = 1; w < 8; ++w) dmax = fmaxf(dmax, red8[w]);

    const int arow = tid >> 4, apart = tid & 15;     // 32 rows x 16 parts of 4
    const float si = srcv[arow];
    float mrow = si + dmax;
    mrow = mrow >= 0.f ? mrow : ALPHA * mrow;
    float fsum = 0.f;

    const int mfrag = wave >> 2, fq = wave & 3;      // 2 x 4 wave-tiles of 16x16
    const ushortT* Bbase = Wh2T + (size_t)(b * DOUT) * NN;
    f32x4 acc4 = (f32x4){0.f, 0.f, 0.f, 0.f};

#define STAGE_A2(kt_, buf_)                                                                \
    {                                                                                      \
        const int kt__ = (kt_);                                                            \
        const unsigned w0 = maskS[arow * 32 + kt__ * 2 + (apart >> 3)];                    \
        const int bb = (apart & 7) * 4;                                                    \
        union { ushortT u[4]; uint2 q; } tw;                                               \
        const float4 dv = *(const float4*)&dstv[kt__ * 64 + apart * 4];                    \
        const float vv[4] = {dv.x, dv.y, dv.z, dv.w};                                      \
        _Pragma("unroll")                                                                  \
        for (int e = 0; e < 4; ++e) {                                                      \
            float v = si + vv[e];                                                          \
            v = v >= 0.f ? v : ALPHA * v;                                                  \
            const unsigned bit = (w0 >> (bb + e)) & 1u;                                    \
            const float p = bit ? __expf(v - mrow) : 0.f;                                  \
            fsum += p;                                                                     \
            tw.u[e] = f2bf(p);                                                             \
        }                                                                                  \
        *(uint2*)&As[(buf_)][arow * 64 + (((apart >> 1) ^ (arow & 7)) * 8) + (apart & 1) * 4] = tw.q; \
    }
#define LOADB2(kt_, dst_)                                                                  \
    {                                                                                      \
        _Pragma("unroll")                                                                  \
        for (int ks = 0; ks < 2; ++ks)                                                     \
            dst_[ks] = *(const bf16x8*)(Bbase +                                            \
                (size_t)(fq * 16 + m16) * NN + (kt_) * 64 + (ks * 4 + quad) * 8);          \
    }
#define MFMA_STEP2(buf_, bv_)                                                              \
    {                                                                                      \
        _Pragma("unroll")                                                                  \
        for (int ks = 0; ks < 2; ++ks) {                                                   \
            const int rowa = mfrag * 16 + m16;                                             \
            const int cla = (ks * 4 + quad) ^ (rowa & 7);                                  \
            const bf16x8 afr = *(const bf16x8*)&As[(buf_)][rowa * 64 + cla * 8];           \
            acc4 = __builtin_amdgcn_mfma_f32_16x16x32_bf16(afr, bv_[ks], acc4, 0, 0, 0);   \
        }                                                                                  \
    }

    bf16x8 b0v[2], b1v[2];
    LOADB2(0, b0v);
    STAGE_A2(0, 0);
    for (int kt = 0; kt < 16; kt += 2) {
        __syncthreads();
        if (kt < 15) { LOADB2(kt + 1, b1v); STAGE_A2(kt + 1, 1); }
        MFMA_STEP2(0, b0v);
        __syncthreads();
        if (kt < 14) { LOADB2(kt + 2, b0v); STAGE_A2(kt + 2, 0); }
        MFMA_STEP2(1, b1v);
    }
#undef STAGE_A2
#undef LOADB2
#undef MFMA_STEP2
#pragma unroll
    for (int o = 1; o < 16; o <<= 1) fsum += __shfl_xor(fsum, o, 64);
    if ((lane & 15) == 0) rowinv[arow] = 1.f / fsum;
    __syncthreads();
    // softmax scale + ELU -> t2s
#pragma unroll
    for (int reg = 0; reg < 4; ++reg) {
        const int row = mfrag * 16 + quad * 4 + reg;
        float v = acc4[reg] * rowinv[row];
        v = v > 0.f ? v : (__expf(v) - 1.f);
        t2s[row * 68 + fq * 16 + m16] = v;
    }
    __syncthreads();
    // FC: out = relu(t2 @ Wf + bf)
    const int cc = fq * 16 + m16;
    f32x4 oacc;
    {
        const float bias = bfv[cc];
        oacc = (f32x4){bias, bias, bias, bias};
    }
#pragma unroll
    for (int ks = 0; ks < 2; ++ks) {
        const int rowa = mfrag * 16 + m16;
        const float4 fA = *(const float4*)&t2s[rowa * 68 + ks * 32 + quad * 8];
        const float4 fB = *(const float4*)&t2s[rowa * 68 + ks * 32 + quad * 8 + 4];
        union { ushortT u[8]; bf16x8 v; } a_h, a_l;
        const float av[8] = {fA.x, fA.y, fA.z, fA.w, fB.x, fB.y, fB.z, fB.w};
#pragma unroll
        for (int e = 0; e < 8; ++e) split2(av[e], a_h.u[e], a_l.u[e]);
        const int cl = (ks * 4 + quad) ^ (cc & 7);
        const bf16x8 b_h = *(const bf16x8*)&Wfh[cc * 64 + cl * 8];
        const bf16x8 b_l = *(const bf16x8*)&Wfl[cc * 64 + cl * 8];
        oacc = __builtin_amdgcn_mfma_f32_16x16x32_bf16(a_h.v, b_h, oacc, 0, 0, 0);
        oacc = __builtin_amdgcn_mfma_f32_16x16x32_bf16(a_h.v, b_l, oacc, 0, 0, 0);
        oacc = __builtin_amdgcn_mfma_f32_16x16x32_bf16(a_l.v, b_h, oacc, 0, 0, 0);
    }
#pragma unroll
    for (int reg = 0; reg < 4; ++reg) {
        const int i = i0 + mfrag * 16 + quad * 4 + reg;
        out[(size_t)(b * NN + i) * DOUT + cc] = fmaxf(oacc[reg], 0.f);
    }
}

extern "C" void kernel_launch(void* const* d_in, const int* in_sizes, int n_in,
                              void* d_out, int out_size, void* d_ws, size_t ws_size,
                              hipStream_t stream) {
    const float* x   = (const float*)d_in[0];
    const int*   adj = (const int*)d_in[1];
    const float* Wh  = (const float*)d_in[2];
    const float* ah  = (const float*)d_in[3];
    const float* Wo  = (const float*)d_in[4];
    const float* ao  = (const float*)d_in[5];
    const float* Wf  = (const float*)d_in[6];
    const float* bf  = (const float*)d_in[7];
    float* out = (float*)d_out;

    float* ws    = (float*)d_ws;
    float* src1  = ws;                                 // 4*8192
    float* dst1  = src1 + NH * RTOT;                   // 4*8192
    float* src2  = dst1 + NH * RTOT;                   // 8192
    float* dst2  = src2 + RTOT;                        // 8192
    ushortT* WhT   = (ushortT*)(dst2 + RTOT);                // 8192*512 bf16
    ushortT* Wh2T  = WhT + (size_t)RTOT * FCAT;              // 8192*64
    ushortT* xcat  = Wh2T + (size_t)RTOT * DOUT;             // 8192*512
    ushortT* WbTh  = xcat + (size_t)RTOT * FCAT;             // 131072
    ushortT* WbTl  = WbTh + NH * DH * DIN;
    ushortT* WoTh  = WbTl + NH * DH * DIN;                   // 32768
    ushortT* WoTl  = WoTh + DOUT * FCAT;
    unsigned* adjbit = (unsigned*)(WoTl + DOUT * FCAT);      // 262144 words
    ushortT* xbh  = (ushortT*)(adjbit + (size_t)BSZ * NN * 32);  // 8192*256 bf16 hi
    ushortT* xbl  = xbh + (size_t)RTOT * DIN;                    // 8192*256 bf16 lo

    hipLaunchKernelGGL(k_prepw, dim3(XBLK + (NH * DH * DIN + DOUT * FCAT) / 256), dim3(256), 0, stream,
                       x, Wh, Wo, xbh, xbl, WbTh, WbTl, WoTh, WoTl);
    hipLaunchKernelGGL(k_main,  dim3(768), dim3(512), 0, stream,
                       xbh, xbl, ah, WbTh, WbTl, adj, adjbit, WhT, src1, dst1);
    hipLaunchKernelGGL(k_attn1, dim3(256), dim3(512), 0, stream,
                       adjbit, WhT, src1, dst1, xcat);
    hipLaunchKernelGGL(k_wh2,   dim3(256), dim3(256), 0, stream,
                       xcat, WoTh, WoTl, ao, Wh2T, src2, dst2);
    hipLaunchKernelGGL(k_attn2, dim3(256), dim3(512), 0, stream,
                       adjbit, Wh2T, src2, dst2, Wf, bf, out);
}